// Round 11
// baseline (322.986 us; speedup 1.0000x reference)
//
#include <hip/hip_runtime.h>

#define Tt 1024
#define Dh 64
#define SCALE 0.125f

typedef __attribute__((ext_vector_type(4))) float f32x4;
typedef __attribute__((ext_vector_type(2))) float f32x2;
typedef __attribute__((ext_vector_type(8))) short bf16x8;
typedef __attribute__((ext_vector_type(4))) short bf16x4;

__device__ inline unsigned short f2bf(float x){
  __bf16 h = (__bf16)x;
  return __builtin_bit_cast(unsigned short, h);
}
__device__ inline float bf2f(unsigned short h){
  return __uint_as_float(((unsigned)h) << 16);
}
__device__ inline ushort4 pack4(float4 f){
  ushort4 u; u.x=f2bf(f.x); u.y=f2bf(f.y); u.z=f2bf(f.z); u.w=f2bf(f.w); return u;
}
__device__ inline bf16x8 pack8(float4 a, float4 b){
  bf16x8 r;
  r[0]=(short)f2bf(a.x); r[1]=(short)f2bf(a.y); r[2]=(short)f2bf(a.z); r[3]=(short)f2bf(a.w);
  r[4]=(short)f2bf(b.x); r[5]=(short)f2bf(b.y); r[6]=(short)f2bf(b.z); r[7]=(short)f2bf(b.w);
  return r;
}
__device__ inline f32x4 mfma16(bf16x8 a, bf16x8 b, f32x4 c){
  return __builtin_amdgcn_mfma_f32_16x16x32_bf16(a, b, c, 0, 0, 0);
}
// 16x16x16 bf16 MFMA (A/B: 4 bf16 per lane; row=lane&15, k=4*(lane>>4)+j)
__device__ inline f32x4 mfma16k16(bf16x4 a, bf16x4 b, f32x4 c){
#if __has_builtin(__builtin_amdgcn_mfma_f32_16x16x16bf16_1k)
  return __builtin_amdgcn_mfma_f32_16x16x16bf16_1k(a, b, c, 0, 0, 0);
#else
  asm volatile("v_mfma_f32_16x16x16_bf16 %0, %1, %2, %0\n\ts_nop 7\n\ts_nop 7"
               : "+v"(c) : "v"(a), "v"(b));
  return c;
#endif
}
// pack 4 f32 * 2^-5 -> 4 fp8 e4m3 in one dword
__device__ inline unsigned pk8f(const float* p){
  int r = __builtin_amdgcn_cvt_pk_fp8_f32(p[0]*0.03125f, p[1]*0.03125f, 0, false);
  r = __builtin_amdgcn_cvt_pk_fp8_f32(p[2]*0.03125f, p[3]*0.03125f, r, true);
  return (unsigned)r;
}
// unpack 4 fp8 (one dword) -> 4 floats
__device__ inline void up8(unsigned v, float* f){
  f32x2 a = __builtin_amdgcn_cvt_pk_f32_fp8((int)v, false);
  f32x2 b = __builtin_amdgcn_cvt_pk_f32_fp8((int)v, true);
  f[0]=a[0]; f[1]=a[1]; f[2]=b[0]; f[3]=b[1];
}

// stage a [64][64] fp32 tile (row stride 64) -> bf16 LDS [64][68]
__device__ inline void stage64x64(const float* __restrict__ g, unsigned short (*lds)[68], int tid){
  int r = tid >> 2, c = (tid & 3) * 16;
  const float4* g4 = (const float4*)(g + (size_t)r * 64 + c);
  float4 f0 = g4[0], f1 = g4[1], f2_ = g4[2], f3 = g4[3];
  ushort4* d4 = (ushort4*)&lds[r][c];
  d4[0]=pack4(f0); d4[1]=pack4(f1); d4[2]=pack4(f2_); d4[3]=pack4(f3);
}
// stage a [64 k][64 d] fp32 tile TRANSPOSED -> lds[d][k] bf16, via 4x4 register-block transpose.
__device__ inline void stage64x64T4(const float* __restrict__ g, unsigned short (*lds)[68], int tid){
  const int kb = (tid >> 4) * 4, db = (tid & 15) * 4;
  float fv[4][4];
#pragma unroll
  for (int j = 0; j < 4; ++j){
    float4 f = *(const float4*)(g + (size_t)(kb + j) * 64 + db);
    fv[j][0]=f.x; fv[j][1]=f.y; fv[j][2]=f.z; fv[j][3]=f.w;
  }
#pragma unroll
  for (int i = 0; i < 4; ++i){
    ushort4 u;
    u.x=f2bf(fv[0][i]); u.y=f2bf(fv[1][i]); u.z=f2bf(fv[2][i]); u.w=f2bf(fv[3][i]);
    *(ushort4*)&lds[db + i][kb] = u;
  }
}
// stage 64 rows x 64 ushorts from global (row stride in ushorts) -> LDS [64][68]
__device__ inline void stage_rows(const unsigned short* __restrict__ g, size_t rowstride,
                                  unsigned short (*lds)[68], int tid){
  int r = tid >> 2, c = (tid & 3) * 16;
  const ushort4* s4 = (const ushort4*)(g + (size_t)r * rowstride + c);
  ushort4 u0=s4[0], u1=s4[1], u2=s4[2], u3=s4[3];
  ushort4* d4 = (ushort4*)&lds[r][c];
  d4[0]=u0; d4[1]=u1; d4[2]=u2; d4[3]=u3;
}
// read 8 consecutive bf16 from lds[row][col..col+7] (col multiple of 8)
__device__ inline bf16x8 ldsfrag(const unsigned short (*lds)[68], int row, int col){
  const ushort4* p = (const ushort4*)&lds[row][col];
  ushort4 u0 = p[0], u1 = p[1];
  bf16x8 r;
  r[0]=(short)u0.x; r[1]=(short)u0.y; r[2]=(short)u0.z; r[3]=(short)u0.w;
  r[4]=(short)u1.x; r[5]=(short)u1.y; r[6]=(short)u1.z; r[7]=(short)u1.w;
  return r;
}

// ---------------- Kernel 1 (swapped): bias^T tile = mfma(Ek_slice, Q_allbh) ----------------
// D cols = bh, D rows = k (4 consecutive per thread) -> direct b64 global stores, no LDS bounce.
__global__ __launch_bounds__(256) void k_qek(const float* __restrict__ Q,
                                             const float* __restrict__ EK,
                                             unsigned short* __restrict__ BIAS){
  __shared__ unsigned short ek[64][68];
  const int qi = blockIdx.x;
  const int tid = threadIdx.x;
  const int w = tid >> 6, l = tid & 63, lr = l & 15, lg = l >> 4;

  // Q B-frags: col = bh = bq*16+lr, k-depth d = lg*8+i (+32)
  bf16x8 qf[4][2];
#pragma unroll
  for (int bq = 0; bq < 4; ++bq){
    const float4* q4 = (const float4*)(Q + ((size_t)(bq*16 + lr) * Tt + qi) * Dh);
    qf[bq][0] = pack8(q4[lg*2],     q4[lg*2 + 1]);
    qf[bq][1] = pack8(q4[8 + lg*2], q4[8 + lg*2 + 1]);
  }
  const float* ekq = EK + (size_t)qi * Tt * Dh;

  for (int kt = 0; kt < 16; ++kt){
    stage64x64(ekq + (size_t)kt * 64 * Dh, ek, tid);
    __syncthreads();
    // A = Ek rows (this wave's 16 k-rows)
    bf16x8 ea0 = ldsfrag(ek, w*16 + lr, lg*8);
    bf16x8 ea1 = ldsfrag(ek, w*16 + lr, lg*8 + 32);
#pragma unroll
    for (int bq = 0; bq < 4; ++bq){
      f32x4 z = {0.f,0.f,0.f,0.f};
      z = mfma16(ea0, qf[bq][0], z);
      z = mfma16(ea1, qf[bq][1], z);
      // D: col=lr -> bh = bq*16+lr ; row=lg*4+j -> k = kt*64 + w*16 + lg*4 + j
      ushort4 u;
      u.x=f2bf(z[0]); u.y=f2bf(z[1]); u.z=f2bf(z[2]); u.w=f2bf(z[3]);
      *(ushort4*)(BIAS + (size_t)(bq*16 + lr) * Tt * Tt + (size_t)qi * Tt
                  + kt*64 + w*16 + lg*4) = u;
    }
    __syncthreads();
  }
}

// ------- Kernel 2 (swapped QK + in-register P): S^T = mfma(K,Q); P never touches LDS.
//         P8 (fp8 e4m3, *2^-5) to global; OUT = (P*V)/rowsum via 16x16x16 PV MFMA. ----
__global__ __launch_bounds__(256) void k_attn(const float* __restrict__ Q,
                                              const float* __restrict__ K,
                                              const float* __restrict__ V,
                                              const unsigned short* __restrict__ BIAS,
                                              unsigned char* __restrict__ P8,
                                              float* __restrict__ OUT){
  __shared__ unsigned short kt_[64][68];
  __shared__ unsigned short bt[64][68];
  __shared__ unsigned short vt[64][68];
  __shared__ float wsum[4][64];
  __shared__ float sums[64];
  __shared__ float scratch[64][68];
  const int bid = blockIdx.x;
  const int bh = (bid & 7) + ((bid >> 7) << 3);   // XCD swizzle: 16 qt-blocks of a bh per XCD
  const int qt = ((bid >> 3) & 15) * 64;
  const int tid = threadIdx.x;
  const int w = tid >> 6, l = tid & 63, lr = l & 15, lg = l >> 4;

  // Q B-frags: col = q = qt + qq*16 + lr, depth d
  bf16x8 qf[4][2];
#pragma unroll
  for (int qq = 0; qq < 4; ++qq){
    const float4* q4 = (const float4*)(Q + ((size_t)bh * Tt + qt + qq*16 + lr) * Dh);
    qf[qq][0] = pack8(q4[lg*2],     q4[lg*2 + 1]);
    qf[qq][1] = pack8(q4[8 + lg*2], q4[8 + lg*2 + 1]);
  }
  const float* kb = K + (size_t)bh * Tt * Dh;
  const float* vb = V + (size_t)bh * Tt * Dh;
  const unsigned short* bsb = BIAS + (size_t)bh * Tt * Tt;
  unsigned char* p8b = P8 + (size_t)bh * Tt * Tt;

  float lsum[4] = {0.f,0.f,0.f,0.f};
  f32x4 oacc[4][4];
#pragma unroll
  for (int a = 0; a < 4; ++a)
#pragma unroll
    for (int b = 0; b < 4; ++b) oacc[a][b] = (f32x4){0.f,0.f,0.f,0.f};

  for (int kt = 0; kt < 16; ++kt){
    stage64x64(kb + (size_t)kt * 64 * Dh, kt_, tid);
    stage_rows(bsb + (size_t)qt * Tt + kt*64, Tt, bt, tid);
    stage64x64T4(vb + (size_t)kt * 64 * Dh, vt, tid);
    __syncthreads();
    // K A-frags: this wave's 16 k-rows only
    bf16x8 ka0 = ldsfrag(kt_, w*16 + lr, lg*8);
    bf16x8 ka1 = ldsfrag(kt_, w*16 + lr, lg*8 + 32);
    // V B-frags (k16): col=d=dq*16+lr, k=4*lg+e within this wave's slice
    bf16x4 vf[4];
#pragma unroll
    for (int dq = 0; dq < 4; ++dq)
      vf[dq] = *(const bf16x4*)&vt[dq*16 + lr][w*16 + lg*4];
#pragma unroll
    for (int qq = 0; qq < 4; ++qq){
      f32x4 z = {0.f,0.f,0.f,0.f};
      z = mfma16(ka0, qf[qq][0], z);
      z = mfma16(ka1, qf[qq][1], z);
      // S^T: thread holds q = qt+qq*16+lr, k = kt*64 + w*16 + lg*4 + j
      ushort4 bv = *(const ushort4*)&bt[qq*16 + lr][w*16 + lg*4];
      float p[4];
      p[0] = __expf((z[0] + bf2f(bv.x)) * SCALE);
      p[1] = __expf((z[1] + bf2f(bv.y)) * SCALE);
      p[2] = __expf((z[2] + bf2f(bv.z)) * SCALE);
      p[3] = __expf((z[3] + bf2f(bv.w)) * SCALE);
      lsum[qq] += p[0] + p[1] + p[2] + p[3];
      // P8 store: 4 k-consecutive fp8 in one dword
      *(unsigned*)(p8b + (size_t)(qt + qq*16 + lr) * Tt + kt*64 + w*16 + lg*4) = pk8f(p);
      // PV A-frag IS the p values (row=q=lr, k=4*lg+j) — in registers
      bf16x4 pf;
      pf[0]=(short)f2bf(p[0]); pf[1]=(short)f2bf(p[1]);
      pf[2]=(short)f2bf(p[2]); pf[3]=(short)f2bf(p[3]);
#pragma unroll
      for (int dq = 0; dq < 4; ++dq)
        oacc[qq][dq] = mfma16k16(pf, vf[dq], oacc[qq][dq]);
    }
    __syncthreads();
  }
  // row sums: reduce over lg (k-groups) then across waves (k-slices)
#pragma unroll
  for (int qq = 0; qq < 4; ++qq){
    float su = lsum[qq];
    su += __shfl_xor(su, 16, 64);
    su += __shfl_xor(su, 32, 64);
    if (lg == 0) wsum[w][qq*16 + lr] = su;
  }
  __syncthreads();
  if (tid < 64) sums[tid] = wsum[0][tid] + wsum[1][tid] + wsum[2][tid] + wsum[3][tid];
  // oacc: 4-way cross-wave reduce into scratch (each wave holds full 64x64 partial)
#pragma unroll
  for (int ww = 0; ww < 4; ++ww){
    __syncthreads();
    if (w == ww){
#pragma unroll
      for (int qq = 0; qq < 4; ++qq)
#pragma unroll
        for (int dq = 0; dq < 4; ++dq)
#pragma unroll
          for (int j = 0; j < 4; ++j){
            float* s = &scratch[qq*16 + lg*4 + j][dq*16 + lr];
            if (ww == 0) *s = oacc[qq][dq][j];
            else         *s += oacc[qq][dq][j];
          }
    }
  }
  __syncthreads();
  // final normalized write, coalesced
  {
    int r = tid >> 2, c4 = (tid & 3) * 16;
    float rlv = 1.f / sums[r];
    float* op = OUT + ((size_t)bh * Tt + qt + r) * Dh + c4;
#pragma unroll
    for (int i = 0; i < 4; ++i){
      float4 v = *(const float4*)&scratch[r][c4 + i*4];
      v.x *= rlv; v.y *= rlv; v.z *= rlv; v.w *= rlv;
      *(float4*)(op + i*4) = v;
    }
  }
}

// ---------------- Kernel 3: OUT[bh,q,d] += (sum_k P*Ev)/rowsum(P), P from fp8 (unchanged) ----------------
__global__ __launch_bounds__(256) void k_aev(const unsigned char* __restrict__ P8,
                                             const float* __restrict__ EV,
                                             float* __restrict__ OUT){
  __shared__ unsigned short evt[2][64][68];
  __shared__ float sums[64];
  const int qi = blockIdx.x;
  const int tid = threadIdx.x;
  const int w = tid >> 6, l = tid & 63, lr = l & 15, lg = l >> 4;

  const unsigned char* arow = P8 + (size_t)(16*w + lr) * Tt * Tt + (size_t)qi * Tt;
  const float* evq = EV + (size_t)qi * Tt * Dh;

  f32x4 acc[4];
#pragma unroll
  for (int c = 0; c < 4; ++c) acc[c] = (f32x4){0.f,0.f,0.f,0.f};
  float asum = 0.f;

  stage64x64T4(evq, evt[0], tid);
  __syncthreads();

  for (int kt = 0; kt < 16; ++kt){
    if (kt < 15) stage64x64T4(evq + (size_t)(kt+1) * 64 * Dh, evt[(kt+1)&1], tid);
    const unsigned short (*cur)[68] = evt[kt&1];
    uint2 ua = *(const uint2*)(arow + kt*64 + lg*8);
    uint2 ub = *(const uint2*)(arow + kt*64 + 32 + lg*8);
    float fa[8], fb[8];
    up8(ua.x, fa); up8(ua.y, fa+4);
    up8(ub.x, fb); up8(ub.y, fb+4);
    bf16x8 a0, a1;
#pragma unroll
    for (int i = 0; i < 8; ++i){
      asum += fa[i] + fb[i];
      a0[i] = (short)f2bf(fa[i]);
      a1[i] = (short)f2bf(fb[i]);
    }
#pragma unroll
    for (int c = 0; c < 4; ++c){
      bf16x8 b0 = ldsfrag(cur, c*16 + lr, lg*8);
      bf16x8 b1 = ldsfrag(cur, c*16 + lr, lg*8 + 32);
      acc[c] = mfma16(a0, b0, acc[c]);
      acc[c] = mfma16(a1, b1, acc[c]);
    }
    __syncthreads();
  }
  asum += __shfl_xor(asum, 16, 64);
  asum += __shfl_xor(asum, 32, 64);
  if (lg == 0) sums[16*w + lr] = asum;
  __builtin_amdgcn_wave_barrier();

#pragma unroll
  for (int c = 0; c < 4; ++c)
#pragma unroll
    for (int j = 0; j < 4; ++j){
      int bh = 16*w + lg*4 + j;
      float rl = 1.f / sums[bh];
      size_t idx = ((size_t)bh * Tt + qi) * Dh + c*16 + lr;
      OUT[idx] += acc[c][j] * rl;
    }
}

extern "C" void kernel_launch(void* const* d_in, const int* in_sizes, int n_in,
                              void* d_out, int out_size, void* d_ws, size_t ws_size,
                              hipStream_t stream){
  const float* Q  = (const float*)d_in[0];
  const float* K  = (const float*)d_in[1];
  const float* V  = (const float*)d_in[2];
  const float* EK = (const float*)d_in[3];
  const float* EV = (const float*)d_in[4];
  float* OUT = (float*)d_out;
  unsigned short* BIAS = (unsigned short*)d_ws;                        // 128 MiB bf16
  unsigned char*  P8   = (unsigned char*)(BIAS + (size_t)64*Tt*Tt);    // 64 MiB fp8

  if (ws_size < (size_t)64*Tt*Tt*sizeof(unsigned short) + (size_t)64*Tt*Tt) return;

  k_qek <<<dim3(1024), dim3(256), 0, stream>>>(Q, EK, BIAS);
  k_attn<<<dim3(1024), dim3(256), 0, stream>>>(Q, K, V, BIAS, P8, OUT);
  k_aev <<<dim3(1024), dim3(256), 0, stream>>>(P8, EV, OUT);
}

// Round 12
// 255.012 us; speedup vs baseline: 1.2666x; 1.2666x over previous
//
#include <hip/hip_runtime.h>

#define Tt 1024
#define Dh 64
#define SCALE 0.125f

typedef __attribute__((ext_vector_type(4))) float f32x4;
typedef __attribute__((ext_vector_type(2))) float f32x2;
typedef __attribute__((ext_vector_type(8))) short bf16x8;

__device__ inline unsigned short f2bf(float x){
  __bf16 h = (__bf16)x;
  return __builtin_bit_cast(unsigned short, h);
}
__device__ inline float bf2f(unsigned short h){
  return __uint_as_float(((unsigned)h) << 16);
}
__device__ inline ushort4 pack4(float4 f){
  ushort4 u; u.x=f2bf(f.x); u.y=f2bf(f.y); u.z=f2bf(f.z); u.w=f2bf(f.w); return u;
}
__device__ inline bf16x8 pack8(float4 a, float4 b){
  bf16x8 r;
  r[0]=(short)f2bf(a.x); r[1]=(short)f2bf(a.y); r[2]=(short)f2bf(a.z); r[3]=(short)f2bf(a.w);
  r[4]=(short)f2bf(b.x); r[5]=(short)f2bf(b.y); r[6]=(short)f2bf(b.z); r[7]=(short)f2bf(b.w);
  return r;
}
__device__ inline f32x4 mfma16(bf16x8 a, bf16x8 b, f32x4 c){
  return __builtin_amdgcn_mfma_f32_16x16x32_bf16(a, b, c, 0, 0, 0);
}
// pack 4 bf16 (as ushort4) * 2^-5 -> 4 fp8 e4m3 in one dword
__device__ inline unsigned pk8(ushort4 u){
  float f0 = bf2f(u.x)*0.03125f, f1 = bf2f(u.y)*0.03125f;
  float f2_ = bf2f(u.z)*0.03125f, f3 = bf2f(u.w)*0.03125f;
  int r = __builtin_amdgcn_cvt_pk_fp8_f32(f0, f1, 0, false);
  r = __builtin_amdgcn_cvt_pk_fp8_f32(f2_, f3, r, true);
  return (unsigned)r;
}
// unpack 4 fp8 (one dword) -> 4 floats
__device__ inline void up8(unsigned v, float* f){
  f32x2 a = __builtin_amdgcn_cvt_pk_f32_fp8((int)v, false);
  f32x2 b = __builtin_amdgcn_cvt_pk_f32_fp8((int)v, true);
  f[0]=a[0]; f[1]=a[1]; f[2]=b[0]; f[3]=b[1];
}

// stage a [64][64] fp32 tile (row stride 64) -> bf16 LDS [64][68]
__device__ inline void stage64x64(const float* __restrict__ g, unsigned short (*lds)[68], int tid){
  int r = tid >> 2, c = (tid & 3) * 16;
  const float4* g4 = (const float4*)(g + (size_t)r * 64 + c);
  float4 f0 = g4[0], f1 = g4[1], f2_ = g4[2], f3 = g4[3];
  ushort4* d4 = (ushort4*)&lds[r][c];
  d4[0]=pack4(f0); d4[1]=pack4(f1); d4[2]=pack4(f2_); d4[3]=pack4(f3);
}
// stage a [64 k][64 d] fp32 tile TRANSPOSED -> lds[d][k] bf16, via 4x4 register-block transpose.
__device__ inline void stage64x64T4(const float* __restrict__ g, unsigned short (*lds)[68], int tid){
  const int kb = (tid >> 4) * 4, db = (tid & 15) * 4;
  float fv[4][4];
#pragma unroll
  for (int j = 0; j < 4; ++j){
    float4 f = *(const float4*)(g + (size_t)(kb + j) * 64 + db);
    fv[j][0]=f.x; fv[j][1]=f.y; fv[j][2]=f.z; fv[j][3]=f.w;
  }
#pragma unroll
  for (int i = 0; i < 4; ++i){
    ushort4 u;
    u.x=f2bf(fv[0][i]); u.y=f2bf(fv[1][i]); u.z=f2bf(fv[2][i]); u.w=f2bf(fv[3][i]);
    *(ushort4*)&lds[db + i][kb] = u;
  }
}
// stage 64 rows x 64 ushorts TRANSPOSED -> lds[col][row], via 4x4 register transpose.
__device__ inline void stage_rowsT4(const unsigned short* __restrict__ g, size_t rowstride,
                                    unsigned short (*lds)[68], int tid){
  const int rb = (tid >> 4) * 4, cb = (tid & 15) * 4;   // rb: q rows, cb: k cols
  ushort4 v[4];
#pragma unroll
  for (int j = 0; j < 4; ++j)
    v[j] = *(const ushort4*)(g + (size_t)(rb + j) * rowstride + cb);
#pragma unroll
  for (int i = 0; i < 4; ++i){
    ushort4 u;
    u.x = ((const unsigned short*)&v[0])[i];
    u.y = ((const unsigned short*)&v[1])[i];
    u.z = ((const unsigned short*)&v[2])[i];
    u.w = ((const unsigned short*)&v[3])[i];
    *(ushort4*)&lds[cb + i][rb] = u;
  }
}
// read 8 consecutive bf16 from lds[row][col..col+7] (col multiple of 8)
__device__ inline bf16x8 ldsfrag(const unsigned short (*lds)[68], int row, int col){
  const ushort4* p = (const ushort4*)&lds[row][col];
  ushort4 u0 = p[0], u1 = p[1];
  bf16x8 r;
  r[0]=(short)u0.x; r[1]=(short)u0.y; r[2]=(short)u0.z; r[3]=(short)u0.w;
  r[4]=(short)u1.x; r[5]=(short)u1.y; r[6]=(short)u1.z; r[7]=(short)u1.w;
  return r;
}

// ---------------- Kernel 1: bias[bh][q][k] = sum_d Q[bh,q,d] * Ek[q,k,d]  (bf16 out) ----------------
// Grid 2048: each block does half the k-range (8 tiles) -> 6 blocks/CU resident (LDS 26KB), better
// latency coverage. Double-buffered EK; ot bounce wave-local.
__global__ __launch_bounds__(256) void k_qek(const float* __restrict__ Q,
                                             const float* __restrict__ EK,
                                             unsigned short* __restrict__ BIAS){
  __shared__ unsigned short ek[2][64][68];
  __shared__ unsigned short ot[4][16][68];
  const int bid = blockIdx.x;
  const int qi = bid >> 1;
  const int k0 = (bid & 1) * 8;
  const int tid = threadIdx.x;
  const int w = tid >> 6, l = tid & 63, lr = l & 15, lg = l >> 4;

  bf16x8 a0, a1;   // A rows bh = 16w+lr, k-dim d = lg*8+i (+32)
  {
    const float4* q4 = (const float4*)(Q + ((size_t)(16*w + lr) * Tt + qi) * Dh);
    a0 = pack8(q4[lg*2],     q4[lg*2 + 1]);
    a1 = pack8(q4[8 + lg*2], q4[8 + lg*2 + 1]);
  }
  const float* ekq = EK + (size_t)qi * Tt * Dh;
  const int r = l >> 2, c2 = (l & 3) * 16;
  unsigned short* dst0 = BIAS + (size_t)(16*w + r) * Tt * Tt + (size_t)qi * Tt + c2;

  stage64x64(ekq + (size_t)k0 * 64 * Dh, ek[0], tid);
  __syncthreads();

  for (int kk = 0; kk < 8; ++kk){
    const int kt = k0 + kk;
    if (kk < 7) stage64x64(ekq + (size_t)(kt+1) * 64 * Dh, ek[(kk+1)&1], tid);
    const unsigned short (*cur)[68] = ek[kk&1];
    f32x4 acc[4];
#pragma unroll
    for (int c = 0; c < 4; ++c){
      bf16x8 b0 = ldsfrag(cur, c*16 + lr, lg*8);
      bf16x8 b1 = ldsfrag(cur, c*16 + lr, lg*8 + 32);
      f32x4 z = {0.f,0.f,0.f,0.f};
      z = mfma16(a0, b0, z);
      z = mfma16(a1, b1, z);
      acc[c] = z;
    }
#pragma unroll
    for (int c = 0; c < 4; ++c)
#pragma unroll
      for (int j = 0; j < 4; ++j)
        ot[w][lg*4 + j][c*16 + lr] = f2bf(acc[c][j]);
    __builtin_amdgcn_wave_barrier();   // wave-local bounce: rows [16w,16w+16) only
    {
      const ushort4* s4 = (const ushort4*)&ot[w][r][c2];
      ushort4 u0=s4[0], u1=s4[1], u2=s4[2], u3=s4[3];
      ushort4* d4 = (ushort4*)(dst0 + kt*64);
      d4[0]=u0; d4[1]=u1; d4[2]=u2; d4[3]=u3;
    }
    __builtin_amdgcn_wave_barrier();
    __syncthreads();
  }
}

// ------- Kernel 2: P = exp((QK^T + bias)/8); out1 = (P*V)/rowsum(P) (bf16 path);
//         P stored fp8 e4m3 *2^-5 for k_aev. Bias staged TRANSPOSED (btT[k][q]) ->
//         4x ds_read_b64 per tile instead of 16 scalar u16 reads. XCD swizzle. ----
__global__ __launch_bounds__(256) void k_attn(const float* __restrict__ Q,
                                              const float* __restrict__ K,
                                              const float* __restrict__ V,
                                              const unsigned short* __restrict__ BIAS,
                                              unsigned char* __restrict__ P8,
                                              float* __restrict__ OUT){
  __shared__ unsigned short kt_[64][68];
  __shared__ unsigned short btT[64][68];   // [k][q]
  __shared__ unsigned short pt[64][68];
  __shared__ unsigned short vt[64][68];
  const int bid = blockIdx.x;
  const int bh = (bid & 7) + ((bid >> 7) << 3);   // bid = (bh&7) + 8*((bh>>3)*16 + qtIdx)
  const int qt = ((bid >> 3) & 15) * 64;
  const int tid = threadIdx.x;
  const int w = tid >> 6, l = tid & 63, lr = l & 15, lg = l >> 4;

  bf16x8 a0, a1;   // A rows q = qt+16w+lr
  {
    const float4* q4 = (const float4*)(Q + ((size_t)bh * Tt + qt + 16*w + lr) * Dh);
    a0 = pack8(q4[lg*2],     q4[lg*2 + 1]);
    a1 = pack8(q4[8 + lg*2], q4[8 + lg*2 + 1]);
  }
  const float* kb = K + (size_t)bh * Tt * Dh;
  const float* vb = V + (size_t)bh * Tt * Dh;
  const unsigned short* bsb = BIAS + (size_t)bh * Tt * Tt;
  unsigned char* p8b = P8 + (size_t)bh * Tt * Tt;

  float lsum[4] = {0.f,0.f,0.f,0.f};
  f32x4 oacc[4];
#pragma unroll
  for (int c = 0; c < 4; ++c) oacc[c] = (f32x4){0.f,0.f,0.f,0.f};

  for (int kt = 0; kt < 16; ++kt){
    stage64x64(kb + (size_t)kt * 64 * Dh, kt_, tid);
    stage_rowsT4(bsb + (size_t)qt * Tt + kt*64, Tt, btT, tid);
    stage64x64T4(vb + (size_t)kt * 64 * Dh, vt, tid);
    __syncthreads();
#pragma unroll
    for (int c = 0; c < 4; ++c){
      bf16x8 b0 = ldsfrag(kt_, c*16 + lr, lg*8);
      bf16x8 b1 = ldsfrag(kt_, c*16 + lr, lg*8 + 32);
      f32x4 z = {0.f,0.f,0.f,0.f};
      z = mfma16(a0, b0, z);
      z = mfma16(a1, b1, z);
      int kl = c*16 + lr;
      ushort4 bv = *(const ushort4*)&btT[kl][16*w + lg*4];   // 4 q-consecutive bias values
      float s0 = (z[0] + bf2f(bv.x)) * SCALE;
      float s1 = (z[1] + bf2f(bv.y)) * SCALE;
      float s2 = (z[2] + bf2f(bv.z)) * SCALE;
      float s3 = (z[3] + bf2f(bv.w)) * SCALE;
      float p0 = __expf(s0), p1 = __expf(s1), p2 = __expf(s2), p3 = __expf(s3);
      lsum[0] += p0; lsum[1] += p1; lsum[2] += p2; lsum[3] += p3;
      pt[16*w + lg*4 + 0][kl] = f2bf(p0);
      pt[16*w + lg*4 + 1][kl] = f2bf(p1);
      pt[16*w + lg*4 + 2][kl] = f2bf(p2);
      pt[16*w + lg*4 + 3][kl] = f2bf(p3);
    }
    __builtin_amdgcn_wave_barrier();   // pt writers == readers (same wave rows)
    // PV first (MFMA issues immediately), then the independent P8 writeout
    bf16x8 p0 = ldsfrag(pt, 16*w + lr, lg*8);
    bf16x8 p1 = ldsfrag(pt, 16*w + lr, lg*8 + 32);
#pragma unroll
    for (int c = 0; c < 4; ++c){
      bf16x8 v0 = ldsfrag(vt, c*16 + lr, lg*8);
      bf16x8 v1 = ldsfrag(vt, c*16 + lr, lg*8 + 32);
      oacc[c] = mfma16(p0, v0, oacc[c]);
      oacc[c] = mfma16(p1, v1, oacc[c]);
    }
    {
      int r = l >> 2, cq = (l & 3);
      const ushort4* s4 = (const ushort4*)&pt[16*w + r][cq*16];
      ushort4 u0=s4[0], u1=s4[1], u2=s4[2], u3=s4[3];
      uint4 o;
      o.x = pk8(u0); o.y = pk8(u1); o.z = pk8(u2); o.w = pk8(u3);
      *(uint4*)(p8b + ((size_t)(qt + 16*w + r) << 10) + kt*64 + cq*16) = o;
    }
    __syncthreads();
  }
  float rl[4];
#pragma unroll
  for (int j = 0; j < 4; ++j){
    float su = lsum[j];
    for (int o = 1; o < 16; o <<= 1) su += __shfl_xor(su, o, 64);
    rl[j] = 1.f / su;
  }
#pragma unroll
  for (int c = 0; c < 4; ++c)
#pragma unroll
    for (int j = 0; j < 4; ++j)
      OUT[((size_t)bh * Tt + qt + 16*w + lg*4 + j) * Dh + c*16 + lr] = oacc[c][j] * rl[j];
}

// ---------------- Kernel 3: OUT[bh,q,d] += (sum_k P*Ev)/rowsum(P), P from fp8 ----------------
__global__ __launch_bounds__(256) void k_aev(const unsigned char* __restrict__ P8,
                                             const float* __restrict__ EV,
                                             float* __restrict__ OUT){
  __shared__ unsigned short evt[2][64][68];
  __shared__ float sums[64];
  const int qi = blockIdx.x;
  const int tid = threadIdx.x;
  const int w = tid >> 6, l = tid & 63, lr = l & 15, lg = l >> 4;

  const unsigned char* arow = P8 + (size_t)(16*w + lr) * Tt * Tt + (size_t)qi * Tt;
  const float* evq = EV + (size_t)qi * Tt * Dh;

  f32x4 acc[4];
#pragma unroll
  for (int c = 0; c < 4; ++c) acc[c] = (f32x4){0.f,0.f,0.f,0.f};
  float asum = 0.f;

  stage64x64T4(evq, evt[0], tid);
  __syncthreads();

  for (int kt = 0; kt < 16; ++kt){
    if (kt < 15) stage64x64T4(evq + (size_t)(kt+1) * 64 * Dh, evt[(kt+1)&1], tid);
    const unsigned short (*cur)[68] = evt[kt&1];
    uint2 ua = *(const uint2*)(arow + kt*64 + lg*8);
    uint2 ub = *(const uint2*)(arow + kt*64 + 32 + lg*8);
    float fa[8], fb[8];
    up8(ua.x, fa); up8(ua.y, fa+4);
    up8(ub.x, fb); up8(ub.y, fb+4);
    bf16x8 a0, a1;
#pragma unroll
    for (int i = 0; i < 8; ++i){
      asum += fa[i] + fb[i];
      a0[i] = (short)f2bf(fa[i]);
      a1[i] = (short)f2bf(fb[i]);
    }
#pragma unroll
    for (int c = 0; c < 4; ++c){
      bf16x8 b0 = ldsfrag(cur, c*16 + lr, lg*8);
      bf16x8 b1 = ldsfrag(cur, c*16 + lr, lg*8 + 32);
      acc[c] = mfma16(a0, b0, acc[c]);
      acc[c] = mfma16(a1, b1, acc[c]);
    }
    __syncthreads();
  }
  asum += __shfl_xor(asum, 16, 64);
  asum += __shfl_xor(asum, 32, 64);
  if (lg == 0) sums[16*w + lr] = asum;
  __builtin_amdgcn_wave_barrier();

#pragma unroll
  for (int c = 0; c < 4; ++c)
#pragma unroll
    for (int j = 0; j < 4; ++j){
      int bh = 16*w + lg*4 + j;
      float rl = 1.f / sums[bh];
      size_t idx = ((size_t)bh * Tt + qi) * Dh + c*16 + lr;
      OUT[idx] += acc[c][j] * rl;
    }
}

extern "C" void kernel_launch(void* const* d_in, const int* in_sizes, int n_in,
                              void* d_out, int out_size, void* d_ws, size_t ws_size,
                              hipStream_t stream){
  const float* Q  = (const float*)d_in[0];
  const float* K  = (const float*)d_in[1];
  const float* V  = (const float*)d_in[2];
  const float* EK = (const float*)d_in[3];
  const float* EV = (const float*)d_in[4];
  float* OUT = (float*)d_out;
  unsigned short* BIAS = (unsigned short*)d_ws;                        // 128 MiB bf16
  unsigned char*  P8   = (unsigned char*)(BIAS + (size_t)64*Tt*Tt);    // 64 MiB fp8

  if (ws_size < (size_t)64*Tt*Tt*sizeof(unsigned short) + (size_t)64*Tt*Tt) return;

  k_qek <<<dim3(2048), dim3(256), 0, stream>>>(Q, EK, BIAS);
  k_attn<<<dim3(1024), dim3(256), 0, stream>>>(Q, K, V, BIAS, P8, OUT);
  k_aev <<<dim3(1024), dim3(256), 0, stream>>>(P8, EV, OUT);
}

// Round 14
// 254.789 us; speedup vs baseline: 1.2677x; 1.0009x over previous
//
#include <hip/hip_runtime.h>

#define Tt 1024
#define Dh 64
#define SCALE 0.125f

typedef __attribute__((ext_vector_type(4))) float f32x4;
typedef __attribute__((ext_vector_type(2))) float f32x2;
typedef __attribute__((ext_vector_type(8))) short bf16x8;

__device__ inline unsigned short f2bf(float x){
  __bf16 h = (__bf16)x;
  return __builtin_bit_cast(unsigned short, h);
}
__device__ inline float bf2f(unsigned short h){
  return __uint_as_float(((unsigned)h) << 16);
}
__device__ inline ushort4 pack4(float4 f){
  ushort4 u; u.x=f2bf(f.x); u.y=f2bf(f.y); u.z=f2bf(f.z); u.w=f2bf(f.w); return u;
}
__device__ inline bf16x8 pack8(float4 a, float4 b){
  bf16x8 r;
  r[0]=(short)f2bf(a.x); r[1]=(short)f2bf(a.y); r[2]=(short)f2bf(a.z); r[3]=(short)f2bf(a.w);
  r[4]=(short)f2bf(b.x); r[5]=(short)f2bf(b.y); r[6]=(short)f2bf(b.z); r[7]=(short)f2bf(b.w);
  return r;
}
__device__ inline f32x4 mfma16(bf16x8 a, bf16x8 b, f32x4 c){
  return __builtin_amdgcn_mfma_f32_16x16x32_bf16(a, b, c, 0, 0, 0);
}
// pack 4 bf16 (as ushort4) * 2^-5 -> 4 fp8 e4m3 in one dword
__device__ inline unsigned pk8(ushort4 u){
  float f0 = bf2f(u.x)*0.03125f, f1 = bf2f(u.y)*0.03125f;
  float f2_ = bf2f(u.z)*0.03125f, f3 = bf2f(u.w)*0.03125f;
  int r = __builtin_amdgcn_cvt_pk_fp8_f32(f0, f1, 0, false);
  r = __builtin_amdgcn_cvt_pk_fp8_f32(f2_, f3, r, true);
  return (unsigned)r;
}
// unpack 4 fp8 (one dword) -> 4 floats
__device__ inline void up8(unsigned v, float* f){
  f32x2 a = __builtin_amdgcn_cvt_pk_f32_fp8((int)v, false);
  f32x2 b = __builtin_amdgcn_cvt_pk_f32_fp8((int)v, true);
  f[0]=a[0]; f[1]=a[1]; f[2]=b[0]; f[3]=b[1];
}

// stage a [64][64] fp32 tile (row stride 64) -> bf16 LDS [64][68]
__device__ inline void stage64x64(const float* __restrict__ g, unsigned short (*lds)[68], int tid){
  int r = tid >> 2, c = (tid & 3) * 16;
  const float4* g4 = (const float4*)(g + (size_t)r * 64 + c);
  float4 f0 = g4[0], f1 = g4[1], f2_ = g4[2], f3 = g4[3];
  ushort4* d4 = (ushort4*)&lds[r][c];
  d4[0]=pack4(f0); d4[1]=pack4(f1); d4[2]=pack4(f2_); d4[3]=pack4(f3);
}
// stage a [64 k][64 d] fp32 tile TRANSPOSED -> lds[d][k] bf16, via 4x4 register-block transpose.
__device__ inline void stage64x64T4(const float* __restrict__ g, unsigned short (*lds)[68], int tid){
  const int kb = (tid >> 4) * 4, db = (tid & 15) * 4;
  float fv[4][4];
#pragma unroll
  for (int j = 0; j < 4; ++j){
    float4 f = *(const float4*)(g + (size_t)(kb + j) * 64 + db);
    fv[j][0]=f.x; fv[j][1]=f.y; fv[j][2]=f.z; fv[j][3]=f.w;
  }
#pragma unroll
  for (int i = 0; i < 4; ++i){
    ushort4 u;
    u.x=f2bf(fv[0][i]); u.y=f2bf(fv[1][i]); u.z=f2bf(fv[2][i]); u.w=f2bf(fv[3][i]);
    *(ushort4*)&lds[db + i][kb] = u;
  }
}
// stage 64 rows x 64 ushorts TRANSPOSED -> lds[col][row], via 4x4 register transpose.
__device__ inline void stage_rowsT4(const unsigned short* __restrict__ g, size_t rowstride,
                                    unsigned short (*lds)[68], int tid){
  const int rb = (tid >> 4) * 4, cb = (tid & 15) * 4;   // rb: q rows, cb: k cols
  ushort4 v[4];
#pragma unroll
  for (int j = 0; j < 4; ++j)
    v[j] = *(const ushort4*)(g + (size_t)(rb + j) * rowstride + cb);
#pragma unroll
  for (int i = 0; i < 4; ++i){
    ushort4 u;
    u.x = ((const unsigned short*)&v[0])[i];
    u.y = ((const unsigned short*)&v[1])[i];
    u.z = ((const unsigned short*)&v[2])[i];
    u.w = ((const unsigned short*)&v[3])[i];
    *(ushort4*)&lds[cb + i][rb] = u;
  }
}
// read 8 consecutive bf16 from lds[row][col..col+7] (col multiple of 8)
__device__ inline bf16x8 ldsfrag(const unsigned short (*lds)[68], int row, int col){
  const ushort4* p = (const ushort4*)&lds[row][col];
  ushort4 u0 = p[0], u1 = p[1];
  bf16x8 r;
  r[0]=(short)u0.x; r[1]=(short)u0.y; r[2]=(short)u0.z; r[3]=(short)u0.w;
  r[4]=(short)u1.x; r[5]=(short)u1.y; r[6]=(short)u1.z; r[7]=(short)u1.w;
  return r;
}

// ---------------- Kernel 1: bias[bh][q][k] = sum_d Q[bh,q,d] * Ek[q,k,d]  (bf16 out) ----------------
// Grid 2048: each block does half the k-range; double-buffered EK; ot bounce wave-local.
__global__ __launch_bounds__(256) void k_qek(const float* __restrict__ Q,
                                             const float* __restrict__ EK,
                                             unsigned short* __restrict__ BIAS){
  __shared__ unsigned short ek[2][64][68];
  __shared__ unsigned short ot[4][16][68];
  const int bid = blockIdx.x;
  const int qi = bid >> 1;
  const int k0 = (bid & 1) * 8;
  const int tid = threadIdx.x;
  const int w = tid >> 6, l = tid & 63, lr = l & 15, lg = l >> 4;

  bf16x8 a0, a1;   // A rows bh = 16w+lr, k-dim d = lg*8+i (+32)
  {
    const float4* q4 = (const float4*)(Q + ((size_t)(16*w + lr) * Tt + qi) * Dh);
    a0 = pack8(q4[lg*2],     q4[lg*2 + 1]);
    a1 = pack8(q4[8 + lg*2], q4[8 + lg*2 + 1]);
  }
  const float* ekq = EK + (size_t)qi * Tt * Dh;
  const int r = l >> 2, c2 = (l & 3) * 16;
  unsigned short* dst0 = BIAS + (size_t)(16*w + r) * Tt * Tt + (size_t)qi * Tt + c2;

  stage64x64(ekq + (size_t)k0 * 64 * Dh, ek[0], tid);
  __syncthreads();

  for (int kk = 0; kk < 8; ++kk){
    const int kt = k0 + kk;
    if (kk < 7) stage64x64(ekq + (size_t)(kt+1) * 64 * Dh, ek[(kk+1)&1], tid);
    const unsigned short (*cur)[68] = ek[kk&1];
    f32x4 acc[4];
#pragma unroll
    for (int c = 0; c < 4; ++c){
      bf16x8 b0 = ldsfrag(cur, c*16 + lr, lg*8);
      bf16x8 b1 = ldsfrag(cur, c*16 + lr, lg*8 + 32);
      f32x4 z = {0.f,0.f,0.f,0.f};
      z = mfma16(a0, b0, z);
      z = mfma16(a1, b1, z);
      acc[c] = z;
    }
#pragma unroll
    for (int c = 0; c < 4; ++c)
#pragma unroll
      for (int j = 0; j < 4; ++j)
        ot[w][lg*4 + j][c*16 + lr] = f2bf(acc[c][j]);
    __builtin_amdgcn_wave_barrier();   // wave-local bounce: rows [16w,16w+16) only
    {
      const ushort4* s4 = (const ushort4*)&ot[w][r][c2];
      ushort4 u0=s4[0], u1=s4[1], u2=s4[2], u3=s4[3];
      ushort4* d4 = (ushort4*)(dst0 + kt*64);
      d4[0]=u0; d4[1]=u1; d4[2]=u2; d4[3]=u3;
    }
    __builtin_amdgcn_wave_barrier();
    __syncthreads();
  }
}

// ------- Kernel 2: P = exp((QK^T + bias)/8); out1 = (P*V)/rowsum(P) (bf16 path);
//         P stored fp8 e4m3 *2^-5 for k_aev. Bias staged TRANSPOSED (btT[k][q]) ->
//         4x ds_read_b64 per tile instead of 16 scalar u16 reads. XCD swizzle. ----
__global__ __launch_bounds__(256) void k_attn(const float* __restrict__ Q,
                                              const float* __restrict__ K,
                                              const float* __restrict__ V,
                                              const unsigned short* __restrict__ BIAS,
                                              unsigned char* __restrict__ P8,
                                              float* __restrict__ OUT){
  __shared__ unsigned short kt_[64][68];
  __shared__ unsigned short btT[64][68];   // [k][q]
  __shared__ unsigned short pt[64][68];
  __shared__ unsigned short vt[64][68];
  const int bid = blockIdx.x;
  const int bh = (bid & 7) + ((bid >> 7) << 3);   // bid = (bh&7) + 8*((bh>>3)*16 + qtIdx)
  const int qt = ((bid >> 3) & 15) * 64;
  const int tid = threadIdx.x;
  const int w = tid >> 6, l = tid & 63, lr = l & 15, lg = l >> 4;

  bf16x8 a0, a1;   // A rows q = qt+16w+lr
  {
    const float4* q4 = (const float4*)(Q + ((size_t)bh * Tt + qt + 16*w + lr) * Dh);
    a0 = pack8(q4[lg*2],     q4[lg*2 + 1]);
    a1 = pack8(q4[8 + lg*2], q4[8 + lg*2 + 1]);
  }
  const float* kb = K + (size_t)bh * Tt * Dh;
  const float* vb = V + (size_t)bh * Tt * Dh;
  const unsigned short* bsb = BIAS + (size_t)bh * Tt * Tt;
  unsigned char* p8b = P8 + (size_t)bh * Tt * Tt;

  float lsum[4] = {0.f,0.f,0.f,0.f};
  f32x4 oacc[4];
#pragma unroll
  for (int c = 0; c < 4; ++c) oacc[c] = (f32x4){0.f,0.f,0.f,0.f};

  for (int kt = 0; kt < 16; ++kt){
    stage64x64(kb + (size_t)kt * 64 * Dh, kt_, tid);
    stage_rowsT4(bsb + (size_t)qt * Tt + kt*64, Tt, btT, tid);
    stage64x64T4(vb + (size_t)kt * 64 * Dh, vt, tid);
    __syncthreads();
#pragma unroll
    for (int c = 0; c < 4; ++c){
      bf16x8 b0 = ldsfrag(kt_, c*16 + lr, lg*8);
      bf16x8 b1 = ldsfrag(kt_, c*16 + lr, lg*8 + 32);
      f32x4 z = {0.f,0.f,0.f,0.f};
      z = mfma16(a0, b0, z);
      z = mfma16(a1, b1, z);
      int kl = c*16 + lr;
      ushort4 bv = *(const ushort4*)&btT[kl][16*w + lg*4];   // 4 q-consecutive bias values
      float s0 = (z[0] + bf2f(bv.x)) * SCALE;
      float s1 = (z[1] + bf2f(bv.y)) * SCALE;
      float s2 = (z[2] + bf2f(bv.z)) * SCALE;
      float s3 = (z[3] + bf2f(bv.w)) * SCALE;
      float p0 = __expf(s0), p1 = __expf(s1), p2 = __expf(s2), p3 = __expf(s3);
      lsum[0] += p0; lsum[1] += p1; lsum[2] += p2; lsum[3] += p3;
      pt[16*w + lg*4 + 0][kl] = f2bf(p0);
      pt[16*w + lg*4 + 1][kl] = f2bf(p1);
      pt[16*w + lg*4 + 2][kl] = f2bf(p2);
      pt[16*w + lg*4 + 3][kl] = f2bf(p3);
    }
    __builtin_amdgcn_wave_barrier();   // pt writers == readers (same wave rows)
    // PV first (MFMA issues immediately), then the independent P8 writeout
    bf16x8 p0 = ldsfrag(pt, 16*w + lr, lg*8);
    bf16x8 p1 = ldsfrag(pt, 16*w + lr, lg*8 + 32);
#pragma unroll
    for (int c = 0; c < 4; ++c){
      bf16x8 v0 = ldsfrag(vt, c*16 + lr, lg*8);
      bf16x8 v1 = ldsfrag(vt, c*16 + lr, lg*8 + 32);
      oacc[c] = mfma16(p0, v0, oacc[c]);
      oacc[c] = mfma16(p1, v1, oacc[c]);
    }
    {
      int r = l >> 2, cq = (l & 3);
      const ushort4* s4 = (const ushort4*)&pt[16*w + r][cq*16];
      ushort4 u0=s4[0], u1=s4[1], u2=s4[2], u3=s4[3];
      uint4 o;
      o.x = pk8(u0); o.y = pk8(u1); o.z = pk8(u2); o.w = pk8(u3);
      *(uint4*)(p8b + ((size_t)(qt + 16*w + r) << 10) + kt*64 + cq*16) = o;
    }
    __syncthreads();
  }
  float rl[4];
#pragma unroll
  for (int j = 0; j < 4; ++j){
    float su = lsum[j];
    for (int o = 1; o < 16; o <<= 1) su += __shfl_xor(su, o, 64);
    rl[j] = 1.f / su;
  }
#pragma unroll
  for (int c = 0; c < 4; ++c)
#pragma unroll
    for (int j = 0; j < 4; ++j)
      OUT[((size_t)bh * Tt + qt + 16*w + lg*4 + j) * Dh + c*16 + lr] = oacc[c][j] * rl[j];
}

// ---------------- Kernel 3: OUT[bh,q,d] += (sum_k P*Ev)/rowsum(P), P from fp8 ----------------
// Row sums recomputed from the SAME fp8 values -> quantization bias cancels in num/denom.
__global__ __launch_bounds__(256) void k_aev(const unsigned char* __restrict__ P8,
                                             const float* __restrict__ EV,
                                             float* __restrict__ OUT){
  __shared__ unsigned short evt[2][64][68];
  __shared__ float sums[64];
  const int qi = blockIdx.x;
  const int tid = threadIdx.x;
  const int w = tid >> 6, l = tid & 63, lr = l & 15, lg = l >> 4;

  const unsigned char* arow = P8 + (size_t)(16*w + lr) * Tt * Tt + (size_t)qi * Tt;
  const float* evq = EV + (size_t)qi * Tt * Dh;

  f32x4 acc[4];
#pragma unroll
  for (int c = 0; c < 4; ++c) acc[c] = (f32x4){0.f,0.f,0.f,0.f};
  float asum = 0.f;

  stage64x64T4(evq, evt[0], tid);
  __syncthreads();

  for (int kt = 0; kt < 16; ++kt){
    if (kt < 15) stage64x64T4(evq + (size_t)(kt+1) * 64 * Dh, evt[(kt+1)&1], tid);
    const unsigned short (*cur)[68] = evt[kt&1];
    uint2 ua = *(const uint2*)(arow + kt*64 + lg*8);
    uint2 ub = *(const uint2*)(arow + kt*64 + 32 + lg*8);
    float fa[8], fb[8];
    up8(ua.x, fa); up8(ua.y, fa+4);
    up8(ub.x, fb); up8(ub.y, fb+4);
    bf16x8 a0, a1;
#pragma unroll
    for (int i = 0; i < 8; ++i){
      asum += fa[i] + fb[i];
      a0[i] = (short)f2bf(fa[i]);
      a1[i] = (short)f2bf(fb[i]);
    }
#pragma unroll
    for (int c = 0; c < 4; ++c){
      bf16x8 b0 = ldsfrag(cur, c*16 + lr, lg*8);
      bf16x8 b1 = ldsfrag(cur, c*16 + lr, lg*8 + 32);
      acc[c] = mfma16(a0, b0, acc[c]);
      acc[c] = mfma16(a1, b1, acc[c]);
    }
    __syncthreads();
  }
  asum += __shfl_xor(asum, 16, 64);
  asum += __shfl_xor(asum, 32, 64);
  if (lg == 0) sums[16*w + lr] = asum;
  __builtin_amdgcn_wave_barrier();

#pragma unroll
  for (int c = 0; c < 4; ++c)
#pragma unroll
    for (int j = 0; j < 4; ++j){
      int bh = 16*w + lg*4 + j;
      float rl = 1.f / sums[bh];
      size_t idx = ((size_t)bh * Tt + qi) * Dh + c*16 + lr;
      OUT[idx] += acc[c][j] * rl;
    }
}

extern "C" void kernel_launch(void* const* d_in, const int* in_sizes, int n_in,
                              void* d_out, int out_size, void* d_ws, size_t ws_size,
                              hipStream_t stream){
  const float* Q  = (const float*)d_in[0];
  const float* K  = (const float*)d_in[1];
  const float* V  = (const float*)d_in[2];
  const float* EK = (const float*)d_in[3];
  const float* EV = (const float*)d_in[4];
  float* OUT = (float*)d_out;
  unsigned short* BIAS = (unsigned short*)d_ws;                        // 128 MiB bf16
  unsigned char*  P8   = (unsigned char*)(BIAS + (size_t)64*Tt*Tt);    // 64 MiB fp8

  if (ws_size < (size_t)64*Tt*Tt*sizeof(unsigned short) + (size_t)64*Tt*Tt) return;

  k_qek <<<dim3(2048), dim3(256), 0, stream>>>(Q, EK, BIAS);
  k_attn<<<dim3(1024), dim3(256), 0, stream>>>(Q, K, V, BIAS, P8, OUT);
  k_aev <<<dim3(1024), dim3(256), 0, stream>>>(P8, EV, OUT);
}